// Round 13
// baseline (142.676 us; speedup 1.0000x reference)
//
#include <hip/hip_runtime.h>
#include <hip/hip_bf16.h>

typedef __bf16 bf16x8 __attribute__((ext_vector_type(8)));
typedef __bf16 bf16x2 __attribute__((ext_vector_type(2)));
typedef float f32x4 __attribute__((ext_vector_type(4)));

#define NROWS 8192
#define HALF_N 4096
#define DIM 128
#define C1 14.42695040888963f    /* (1/T) * log2(e) */
#define LN2 0.6931471805599453f
#define GBLK 4096                /* 128 rg-quads x 32 col-splits */

/* Packed MFMA-operand layout (R12-verified): rows in groups of 16; group g
   (4096 B) holds rows [g*16,+16). Within a group: 4 ks-regions of 1024 B;
   byte lane*16 of region ks = chunk (ks*4 + lane>>4) of row (g*16+(lane&15)).
   One wave fragment load = one fully-coalesced 1 KB global_load_dwordx4. */

// ---- kernel 1: normalize (i,j) pairs -> packA(=rn*C1), packB(=rn); p_k ----
__global__ __launch_bounds__(256) void k_normalize(
    const float* __restrict__ zi, const float* __restrict__ zj,
    char* __restrict__ packA, char* __restrict__ packB,
    float* __restrict__ rowsum, float* __restrict__ pbuf,
    unsigned int* __restrict__ done)
{
    const int wave = threadIdx.x >> 6;
    const int lane = threadIdx.x & 63;
    const int ks_  = lane >> 4;
    const int qr_  = (lane >> 2) & 3;
    const int rem_ = (lane & 3) * 4;
    #pragma unroll
    for (int t = 0; t < 2; ++t) {
        const int idx = blockIdx.x * 8 + wave * 2 + t;   // i-row; partner idx+N
        float2 vi = *(const float2*)(zi + (size_t)idx * DIM + lane * 2);
        float2 vj = *(const float2*)(zj + (size_t)idx * DIM + lane * 2);
        float ssi = vi.x * vi.x + vi.y * vi.y;
        float ssj = vj.x * vj.x + vj.y * vj.y;
        float cr  = vi.x * vj.x + vi.y * vj.y;
        #pragma unroll
        for (int m = 32; m >= 1; m >>= 1) {
            ssi += __shfl_xor(ssi, m, 64);
            ssj += __shfl_xor(ssj, m, 64);
            cr  += __shfl_xor(cr,  m, 64);
        }
        const float sci = 1.0f / fmaxf(sqrtf(ssi), 1e-8f);
        const float scj = 1.0f / fmaxf(sqrtf(ssj), 1e-8f);
        #pragma unroll
        for (int h = 0; h < 2; ++h) {                 // h=0: i-row, h=1: j-row
            const int   row = idx + h * HALF_N;
            const float sx  = h ? vj.x * scj : vi.x * sci;
            const float sy  = h ? vj.y * scj : vi.y * sci;
            const size_t off = (size_t)(row >> 4) * 4096 + ks_ * 1024
                             + (qr_ * 16 + (row & 15)) * 16 + rem_;
            bf16x2 a, b;
            a[0] = (__bf16)(sx * C1); a[1] = (__bf16)(sy * C1);
            b[0] = (__bf16)sx;        b[1] = (__bf16)sy;
            *(bf16x2*)(packA + off) = a;
            *(bf16x2*)(packB + off) = b;
        }
        if (lane == 0) {
            const float p = cr * sci * scj;
            pbuf[idx] = p;
            pbuf[idx + HALF_N] = p;
        }
    }
    if (threadIdx.x < 16) rowsum[blockIdx.x * 16 + threadIdx.x] = 0.0f;
    if (blockIdx.x == 0 && threadIdx.x == 0) *done = 0u;
}

// ---- kernel 2: 8-waves/SIMD sim GEMM + exp rowsum + fused finalize ---------
// Strip per wave: 16 rows x 256 cols (R12 at 64-row strips had ~136 unified
// regs/wave -> only 3 waves/SIMD resident -> latency exposed; time invariant
// R8->R12 proves TLP-starvation). Now afrag[4]+acc = 20 AGPR, bfrag 16 +
// rsum 4 + addr ~16 VGPR ~= 56 total -> 8 waves/SIMD. Tiny per-step chain
// (4 loads + 4 MFMA + 4 exp2) interleaved 8-way. Same-cs blocks land on the
// same XCD (cs%8) -> per-XCD L2 holds its 4 B-splits + all A (2.25 MB).
__global__ __launch_bounds__(256, 8) void k_gemm(
    const char* __restrict__ packA, const char* __restrict__ packB,
    float* __restrict__ rowsum, const float* __restrict__ pbuf,
    unsigned int* __restrict__ done, float* __restrict__ out)
{
    const int wave = threadIdx.x >> 6;
    const int lane = threadIdx.x & 63;
    const int qrow = lane >> 4, lcol = lane & 15;
    const int cv = blockIdx.x & 31;                   // 32 col-splits of 256
    const int rg = (blockIdx.x >> 5) * 4 + wave;      // 512 row-groups of 16

    // A fragment: exactly one packed group, 4 coalesced 1 KB loads
    const char* Ab = packA + (size_t)rg * 4096 + lane * 16;
    bf16x8 afrag[4];
    #pragma unroll
    for (int ks = 0; ks < 4; ++ks)
        afrag[ks] = *(const bf16x8*)(Ab + ks * 1024);

    float rsum[4] = {0.0f, 0.0f, 0.0f, 0.0f};
    const char* Bb = packB + (size_t)(cv * 16) * 4096 + lane * 16;

    #pragma unroll 1
    for (int s = 0; s < 16; ++s) {                    // 16 steps of 16 cols
        const char* bp = Bb + (size_t)s * 4096;
        bf16x8 bfrag[4];
        #pragma unroll
        for (int ks = 0; ks < 4; ++ks)
            bfrag[ks] = *(const bf16x8*)(bp + ks * 1024);

        f32x4 acc = {0.0f, 0.0f, 0.0f, 0.0f};
        #pragma unroll
        for (int ks = 0; ks < 4; ++ks)
            acc = __builtin_amdgcn_mfma_f32_16x16x32_bf16(
                afrag[ks], bfrag[ks], acc, 0, 0, 0);

        // rowsum += 2^(s*C1); acc holds s*C1 via pre-scaled A
        #pragma unroll
        for (int r = 0; r < 4; ++r)
            rsum[r] += __builtin_amdgcn_exp2f(acc[r]);
    }

    // reduce over the 16 col-lanes, one atomic per row
    #pragma unroll
    for (int r = 0; r < 4; ++r) {
        float v = rsum[r];
        v += __shfl_xor(v, 1, 64);
        v += __shfl_xor(v, 2, 64);
        v += __shfl_xor(v, 4, 64);
        v += __shfl_xor(v, 8, 64);
        if (lcol == 0)
            atomicAdd(&rowsum[rg * 16 + qrow * 4 + r], v);
    }

    // ---- last-block finalize; no producer-side fence (R11/R12-validated) ---
    __syncthreads();            // compiler drains vmcnt(0) before s_barrier
    __shared__ int is_last;
    if (threadIdx.x == 0) {
        unsigned old = __hip_atomic_fetch_add(done, 1u, __ATOMIC_RELAXED,
                                              __HIP_MEMORY_SCOPE_AGENT);
        is_last = (old == GBLK - 1);
    }
    __syncthreads();
    if (!is_last) return;
    __threadfence();            // acquire side only, once

    // loss_k = (log2(rowsum_k + 2^(p*C1)) - p*C1) * ln2   [v_log_f32 is LOG2]
    float lsum = 0.0f;
    for (int r = threadIdx.x; r < NROWS; r += 256) {
        float rs = __hip_atomic_load(&rowsum[r], __ATOMIC_RELAXED, __HIP_MEMORY_SCOPE_AGENT);
        float pc = pbuf[r] * C1;
        float S  = rs + __builtin_amdgcn_exp2f(pc);
        lsum += (__builtin_amdgcn_logf(S) - pc) * LN2;
    }
    #pragma unroll
    for (int m = 32; m >= 1; m >>= 1) lsum += __shfl_xor(lsum, m, 64);
    __shared__ float part[4];
    if (lane == 0) part[wave] = lsum;
    __syncthreads();
    if (threadIdx.x == 0)
        out[0] = (part[0] + part[1] + part[2] + part[3]) * (1.0f / (float)NROWS);
}

extern "C" void kernel_launch(void* const* d_in, const int* in_sizes, int n_in,
                              void* d_out, int out_size, void* d_ws, size_t ws_size,
                              hipStream_t stream)
{
    const float* zi = (const float*)d_in[0];
    const float* zj = (const float*)d_in[1];
    float* out = (float*)d_out;

    // ws: packA 2MB | packB 2MB | rowsum f32[8192] | pbuf f32[8192] | done
    char*  packA  = (char*)d_ws;
    char*  packB  = packA + (size_t)NROWS * 256;
    float* rowsum = (float*)(packB + (size_t)NROWS * 256);
    float* pbuf   = rowsum + NROWS;
    unsigned int* done = (unsigned int*)(pbuf + NROWS);

    k_normalize<<<NROWS / 16, 256, 0, stream>>>(zi, zj, packA, packB, rowsum, pbuf, done);
    k_gemm<<<GBLK, 256, 0, stream>>>(packA, packB, rowsum, pbuf, done, out);
}

// Round 14
// 96.101 us; speedup vs baseline: 1.4846x; 1.4846x over previous
//
#include <hip/hip_runtime.h>
#include <hip/hip_bf16.h>

typedef float f32x4 __attribute__((ext_vector_type(4)));

#define NROWS 8192
#define HALF_N 4096
#define DIM 128
#define C1 14.42695040888963f    /* (1/T) * log2(e) */
#define LN2 0.6931471805599453f
#define GBLK 1024                /* 32 rg-quads x 32 col-splits */

/* fp8 packed MFMA-operand layout: rows in groups of 16; group g (2048 B)
   holds rows [g*16,+16). Within a group: 4 ks-regions of 512 B; byte lane*8
   of region ks = 8-value chunk (k = ks*32 + (lane>>4)*8 + j) of row
   (g*16 + (lane&15)). One wave fragment load = one fully-coalesced 512 B
   global_load_dwordx2. A and B share this exact mapping, so any intra-dot
   k-permutation inside the fp8 fragment cancels (s = sum over k). */

// ---- kernel 1: normalize (i,j) pairs -> packA(=rn*C1 fp8), packB(=rn fp8) --
__global__ __launch_bounds__(256) void k_normalize(
    const float* __restrict__ zi, const float* __restrict__ zj,
    char* __restrict__ packA, char* __restrict__ packB,
    float* __restrict__ rowsum, float* __restrict__ pbuf,
    unsigned int* __restrict__ done)
{
    const int wave = threadIdx.x >> 6;
    const int lane = threadIdx.x & 63;
    const int ks_  = lane >> 4;
    const int qr_  = (lane >> 2) & 3;
    const int rem_ = (lane & 3) * 2;          // byte pos of this lane's 2 vals
    #pragma unroll
    for (int t = 0; t < 2; ++t) {
        const int idx = blockIdx.x * 8 + wave * 2 + t;   // i-row; partner idx+N
        float2 vi = *(const float2*)(zi + (size_t)idx * DIM + lane * 2);
        float2 vj = *(const float2*)(zj + (size_t)idx * DIM + lane * 2);
        float ssi = vi.x * vi.x + vi.y * vi.y;
        float ssj = vj.x * vj.x + vj.y * vj.y;
        float cr  = vi.x * vj.x + vi.y * vj.y;
        #pragma unroll
        for (int m = 32; m >= 1; m >>= 1) {
            ssi += __shfl_xor(ssi, m, 64);
            ssj += __shfl_xor(ssj, m, 64);
            cr  += __shfl_xor(cr,  m, 64);
        }
        const float sci = 1.0f / fmaxf(sqrtf(ssi), 1e-8f);
        const float scj = 1.0f / fmaxf(sqrtf(ssj), 1e-8f);
        #pragma unroll
        for (int h = 0; h < 2; ++h) {                 // h=0: i-row, h=1: j-row
            const int   row = idx + h * HALF_N;
            const float sx  = h ? vj.x * scj : vi.x * sci;
            const float sy  = h ? vj.y * scj : vi.y * sci;
            const size_t off = (size_t)(row >> 4) * 2048 + ks_ * 512
                             + (qr_ * 16 + (row & 15)) * 8 + rem_;
            unsigned ua = __builtin_amdgcn_cvt_pk_fp8_f32(sx * C1, sy * C1, 0, false);
            unsigned ub = __builtin_amdgcn_cvt_pk_fp8_f32(sx,      sy,      0, false);
            *(unsigned short*)(packA + off) = (unsigned short)ua;
            *(unsigned short*)(packB + off) = (unsigned short)ub;
        }
        if (lane == 0) {
            const float p = cr * sci * scj;   // exact f32 positive-pair cosine
            pbuf[idx] = p;
            pbuf[idx + HALF_N] = p;
        }
    }
    if (threadIdx.x < 16) rowsum[blockIdx.x * 16 + threadIdx.x] = 0.0f;
    if (blockIdx.x == 0 && threadIdx.x == 0) *done = 0u;
}

// ---- kernel 2: wave-independent fp8 sim GEMM + exp rowsum + finalize -------
// R12's proven tiling (64-row x 256-col strips, grid 1024) with HALF the
// bytes: fp8 fragments, 512 B coalesced dwordx2 loads. R12/R13 established
// the limiter is bytes-through-vmem per CU (~10-20 B/cyc), so halving bytes
// is the only remaining lever. MFMA fp8 16x16x32 = bf16 rate.
__global__ __launch_bounds__(256, 4) void k_gemm(
    const char* __restrict__ packA, const char* __restrict__ packB,
    float* __restrict__ rowsum, const float* __restrict__ pbuf,
    unsigned int* __restrict__ done, float* __restrict__ out)
{
    const int wave = threadIdx.x >> 6;
    const int lane = threadIdx.x & 63;
    const int qrow = lane >> 4, lcol = lane & 15;
    const int cv = blockIdx.x & 31;                   // 32 col-splits of 256
    const int rg = (blockIdx.x >> 5) * 4 + wave;      // 128 row-groups of 64

    // A fragments: 16 coalesced 512 B loads (rows rg*64..+63, all K), 32 VGPR
    long afrag[4][4];
    #pragma unroll
    for (int mi = 0; mi < 4; ++mi)
        #pragma unroll
        for (int ks = 0; ks < 4; ++ks)
            afrag[mi][ks] = *(const long*)(packA
                + (size_t)(rg * 4 + mi) * 2048 + ks * 512 + lane * 8);

    float rsum[4][4];
    #pragma unroll
    for (int mi = 0; mi < 4; ++mi)
        #pragma unroll
        for (int r = 0; r < 4; ++r) rsum[mi][r] = 0.0f;

    const char* Bb = packB + (size_t)(cv * 16) * 2048 + lane * 8;

    #pragma unroll 1
    for (int s = 0; s < 16; ++s) {                    // 16 steps of 16 cols
        const char* bp = Bb + (size_t)s * 2048;
        long bfrag[4];
        #pragma unroll
        for (int ks = 0; ks < 4; ++ks)
            bfrag[ks] = *(const long*)(bp + ks * 512);

        f32x4 acc[4];
        const f32x4 zero = {0.0f, 0.0f, 0.0f, 0.0f};
        #pragma unroll
        for (int mi = 0; mi < 4; ++mi) acc[mi] = zero;
        #pragma unroll
        for (int ks = 0; ks < 4; ++ks)
            #pragma unroll
            for (int mi = 0; mi < 4; ++mi)
                acc[mi] = __builtin_amdgcn_mfma_f32_16x16x32_fp8_fp8(
                    afrag[mi][ks], bfrag[ks], acc[mi], 0, 0, 0);

        // rowsum += 2^(s*C1); acc already holds s*C1 via pre-scaled A
        #pragma unroll
        for (int mi = 0; mi < 4; ++mi)
            #pragma unroll
            for (int r = 0; r < 4; ++r)
                rsum[mi][r] += __builtin_amdgcn_exp2f(acc[mi][r]);
    }

    // reduce over the 16 col-lanes, one atomic per row
    #pragma unroll
    for (int mi = 0; mi < 4; ++mi)
        #pragma unroll
        for (int r = 0; r < 4; ++r) {
            float v = rsum[mi][r];
            v += __shfl_xor(v, 1, 64);
            v += __shfl_xor(v, 2, 64);
            v += __shfl_xor(v, 4, 64);
            v += __shfl_xor(v, 8, 64);
            if (lcol == 0)
                atomicAdd(&rowsum[rg * 64 + mi * 16 + qrow * 4 + r], v);
        }

    // ---- last-block finalize; no producer-side fence (R11/R12-validated) ---
    __syncthreads();            // compiler drains vmcnt(0) before s_barrier
    __shared__ int is_last;
    if (threadIdx.x == 0) {
        unsigned old = __hip_atomic_fetch_add(done, 1u, __ATOMIC_RELAXED,
                                              __HIP_MEMORY_SCOPE_AGENT);
        is_last = (old == GBLK - 1);
    }
    __syncthreads();
    if (!is_last) return;
    __threadfence();            // acquire side only, once

    // loss_k = (log2(rowsum_k + 2^(p*C1)) - p*C1) * ln2   [v_log_f32 is LOG2]
    float lsum = 0.0f;
    for (int r = threadIdx.x; r < NROWS; r += 256) {
        float rs = __hip_atomic_load(&rowsum[r], __ATOMIC_RELAXED, __HIP_MEMORY_SCOPE_AGENT);
        float pc = pbuf[r] * C1;
        float S  = rs + __builtin_amdgcn_exp2f(pc);
        lsum += (__builtin_amdgcn_logf(S) - pc) * LN2;
    }
    #pragma unroll
    for (int m = 32; m >= 1; m >>= 1) lsum += __shfl_xor(lsum, m, 64);
    __shared__ float part[4];
    if (lane == 0) part[wave] = lsum;
    __syncthreads();
    if (threadIdx.x == 0)
        out[0] = (part[0] + part[1] + part[2] + part[3]) * (1.0f / (float)NROWS);
}

extern "C" void kernel_launch(void* const* d_in, const int* in_sizes, int n_in,
                              void* d_out, int out_size, void* d_ws, size_t ws_size,
                              hipStream_t stream)
{
    const float* zi = (const float*)d_in[0];
    const float* zj = (const float*)d_in[1];
    float* out = (float*)d_out;

    // ws: packA 1MB | packB 1MB | rowsum f32[8192] | pbuf f32[8192] | done
    char*  packA  = (char*)d_ws;
    char*  packB  = packA + (size_t)NROWS * 128;
    float* rowsum = (float*)(packB + (size_t)NROWS * 128);
    float* pbuf   = rowsum + NROWS;
    unsigned int* done = (unsigned int*)(pbuf + NROWS);

    k_normalize<<<NROWS / 16, 256, 0, stream>>>(zi, zj, packA, packB, rowsum, pbuf, done);
    k_gemm<<<GBLK, 256, 0, stream>>>(packA, packB, rowsum, pbuf, done, out);
}